// Round 6
// baseline (257.057 us; speedup 1.0000x reference)
//
#include <hip/hip_runtime.h>
#include <hip/hip_cooperative_groups.h>

namespace cg = cooperative_groups;

typedef short bf16x8 __attribute__((ext_vector_type(8)));
typedef float f32x4 __attribute__((ext_vector_type(4)));

#define MFMA16(a, b, c) __builtin_amdgcn_mfma_f32_16x16x32_bf16(a, b, c, 0, 0, 0)

__device__ inline short f2bf(float f) {  // RNE
  unsigned u = __builtin_bit_cast(unsigned, f);
  u += 0x7FFFu + ((u >> 16) & 1u);
  return (short)(u >> 16);
}
// two fp32 -> 2 bf16 in one dword; round-half-up then v_perm byte-pack.
__device__ inline unsigned pack2(float lo, float hi) {
  unsigned a = __builtin_bit_cast(unsigned, lo) + 0x8000u;
  unsigned b = __builtin_bit_cast(unsigned, hi) + 0x8000u;
  return __builtin_amdgcn_perm(b, a, 0x07060302u);
}
// Async 16B global->LDS; lds ptr = wave-uniform lane-0 base, HW writes base+16*lane.
__device__ inline void async_cp16(const void* g, void* l) {
  __builtin_amdgcn_global_load_lds(
      (const __attribute__((address_space(1))) unsigned int*)g,
      (__attribute__((address_space(3))) unsigned int*)l, 16, 0, 0);
}
// XOR-swizzled LDS tile: slot (r,c) holds global chunk c^(r&7). Staging lane-linear
// (conflict-free); frag ds_read_b128 spreads 8 lanes per 4-bank group (minimum).
#define SWZ(r, c) ((((r) << 4) + ((c) ^ ((r) & 7))) << 3)

// ---------------------------------------------------------------------------
// ws layout (bytes) — poison outside written regions is finite bf16, audited safe:
//   xmaj_bf  0        : 256x2048 bf16   (rows>=210 poison, feeds discarded acc rows)
//   xmin_bf  1048576  : 256x2048 bf16
//   qs       2097152  : 256x1024 bf16   Qs (pre-scaled 1/32); rows>=210 poison
//   kwb      2621440  : 320x1024 bf16   0..209=K, 210..274=wk, 275..287=0, 288+ poison
//   vt       3276800  : 1024x256 bf16   V^T [n][m], cols>=210 poison (never read)
//   Abf      3801088  : 256x256  bf16   A padded, zeros outside 210x210
//   av       3932160  : 256x1024 bf16   A@V, rows>=210 poison (feeds discarded rows)
//   wqt      4743168  : 1024x2048 bf16  Wq^T
//   wkt      8937472  : 1024x2048 bf16  Wk^T
//   wvt      13131776 : 1024x2048 bf16  Wv^T
//   wot      17326080 : 1024x1024 bf16  Wo^T
// ---------------------------------------------------------------------------

// Single cooperative kernel: 192 blocks x 256 threads, 90112 B LDS (1 block/CU).
// Phases separated by grid.sync(): prep -> QKV -> S'+softmax -> AV -> Y.
__global__ __launch_bounds__(256, 1) void k_fused(const float* __restrict__ xmajf,
                                                  const float* __restrict__ xminf,
                                                  const float* __restrict__ Wqf,
                                                  const float* __restrict__ Wkf,
                                                  const float* __restrict__ Wvf,
                                                  const float* __restrict__ Wof,
                                                  const float* __restrict__ wkin,
                                                  const int* __restrict__ table,
                                                  char* __restrict__ ws,
                                                  float* __restrict__ dout) {
  __shared__ char smem[90112];
  cg::grid_group gg = cg::this_grid();
  int b = blockIdx.x, t = threadIdx.x;
  int lane = t & 63, w = t >> 6;
  int l15 = lane & 15, l4 = lane >> 4;

  short* xmaj_bf = (short*)(ws);
  short* xmin_bf = (short*)(ws + 1048576);
  short* qs = (short*)(ws + 2097152);
  short* kwb = (short*)(ws + 2621440);
  short* vt = (short*)(ws + 3276800);
  short* Abf = (short*)(ws + 3801088);
  short* av = (short*)(ws + 3932160);
  short* wqt = (short*)(ws + 4743168);
  short* wkt = (short*)(ws + 8937472);
  short* wvt = (short*)(ws + 13131776);
  short* wot = (short*)(ws + 17326080);
  float* outY = dout;            // 210*1024 fp32
  float* outA = dout + 215040;   // 210*210 fp32

  // ========== phase 0: convert X/wk, transpose+convert weights ==========
  {
    for (int i = b * 256 + t; i < 107520; i += 49152) {  // 210*2048/4
      float4 v = ((const float4*)xmajf)[i];
      ((uint2*)xmaj_bf)[i] = make_uint2(pack2(v.x, v.y), pack2(v.z, v.w));
      float4 u = ((const float4*)xminf)[i];
      ((uint2*)xmin_bf)[i] = make_uint2(pack2(u.x, u.y), pack2(u.z, u.w));
    }
    for (int i = b * 256 + t; i < 16640; i += 49152) {  // 65*1024/4
      float4 v = ((const float4*)wkin)[i];
      ((uint2*)(kwb + 210 * 1024))[i] = make_uint2(pack2(v.x, v.y), pack2(v.z, v.w));
    }
    for (int i = b * 256 + t; i < 1664; i += 49152)  // zero kwb rows 275..287
      ((uint4*)(kwb + 275 * 1024))[i] = make_uint4(0, 0, 0, 0);

    short(*tile)[72] = (short(*)[72])smem;  // 9216 B
    int kp = t >> 4, nl4 = (t & 15) * 4;
    int nl = t >> 2, cq = t & 3;
    for (int tid = b; tid < 1792; tid += 192) {  // 1792 64x64 weight tiles
      const float* W;
      short* Wt;
      int kt, nt, dstK;
      if (tid < 1536) {
        int wi = tid >> 9, tl = tid & 511;
        W = wi == 0 ? Wqf : (wi == 1 ? Wkf : Wvf);
        Wt = wi == 0 ? wqt : (wi == 1 ? wkt : wvt);
        kt = tl >> 4; nt = tl & 15; dstK = 2048;
      } else {
        int tl = tid - 1536;
        W = Wof; Wt = wot; kt = tl >> 4; nt = tl & 15; dstK = 1024;
      }
      int k0 = kt * 64, n0 = nt * 64;
      __syncthreads();
#pragma unroll
      for (int h = 0; h < 2; ++h) {
        int kpp = kp + h * 16;
        const float* g = W + (size_t)(k0 + 2 * kpp) * 1024 + n0 + nl4;
        float4 u = *(const float4*)g;
        float4 v = *(const float4*)(g + 1024);
        *(unsigned*)&tile[nl4 + 0][2 * kpp] = pack2(u.x, v.x);
        *(unsigned*)&tile[nl4 + 1][2 * kpp] = pack2(u.y, v.y);
        *(unsigned*)&tile[nl4 + 2][2 * kpp] = pack2(u.z, v.z);
        *(unsigned*)&tile[nl4 + 3][2 * kpp] = pack2(u.w, v.w);
      }
      __syncthreads();
#pragma unroll
      for (int h = 0; h < 2; ++h) {
        int c = cq + h * 4;
        *(uint4*)(Wt + (size_t)(n0 + nl) * dstK + k0 + c * 8) = *(const uint4*)&tile[nl][c * 8];
      }
    }
  }
  gg.sync();

  // ========== phase 1: QKV GEMM (all 192 blocks) ==========
  {
    short* As = (short*)smem;             // 64x128 = 16 KB
    short* Bs = (short*)(smem + 16384);   // 64x128 = 16 KB
    int x = b & 7, s = b >> 3;
    int ntile = x * 6 + (s >> 2), mtile = s & 3;
    int nn0 = ntile * 64;
    int mat = nn0 >> 10, ncol0 = nn0 & 1023, m0 = mtile * 64;
    const short* A = (mat == 0) ? xmaj_bf : xmin_bf;
    const short* Bt = (mat == 0) ? wqt : (mat == 1 ? wkt : wvt);
    int wm = w >> 1, wn = w & 1;
    f32x4 acc[2][2] = {};

    for (int k0 = 0; k0 < 2048; k0 += 128) {
      __syncthreads();
#pragma unroll
      for (int j = 0; j < 4; ++j) {
        int sj = t + j * 256;
        int r = sj >> 4, cg2 = (sj & 15) ^ (r & 7);
        async_cp16(A + (size_t)(m0 + r) * 2048 + k0 + cg2 * 8, &As[(w * 64 + j * 256) * 8]);
      }
#pragma unroll
      for (int j = 0; j < 4; ++j) {
        int sj = t + j * 256;
        int r = sj >> 4, cg2 = (sj & 15) ^ (r & 7);
        async_cp16(Bt + (size_t)(ncol0 + r) * 2048 + k0 + cg2 * 8, &Bs[(w * 64 + j * 256) * 8]);
      }
      __syncthreads();
#pragma unroll
      for (int kk = 0; kk < 4; ++kk) {
        int c = kk * 4 + l4;
        int ra0 = wm * 32 + l15, ra1 = ra0 + 16;
        int rb0 = wn * 32 + l15, rb1 = rb0 + 16;
        bf16x8 a0 = *(const bf16x8*)&As[SWZ(ra0, c)];
        bf16x8 a1 = *(const bf16x8*)&As[SWZ(ra1, c)];
        bf16x8 b0 = *(const bf16x8*)&Bs[SWZ(rb0, c)];
        bf16x8 b1 = *(const bf16x8*)&Bs[SWZ(rb1, c)];
        acc[0][0] = MFMA16(a0, b0, acc[0][0]);
        acc[0][1] = MFMA16(a0, b1, acc[0][1]);
        acc[1][0] = MFMA16(a1, b0, acc[1][0]);
        acc[1][1] = MFMA16(a1, b1, acc[1][1]);
      }
    }

    if (mat < 2) {
      float scale = (mat == 0) ? 0.03125f : 1.0f;
      short* dst = (mat == 0) ? qs : kwb;
#pragma unroll
      for (int mi = 0; mi < 2; ++mi)
#pragma unroll
        for (int ni = 0; ni < 2; ++ni) {
          int r0 = m0 + wm * 32 + mi * 16 + l4 * 4;
          int c = ncol0 + wn * 32 + ni * 16 + l15;
          for (int j = 0; j < 4; ++j) {
            int r = r0 + j;
            if (r < 210) dst[r * 1024 + c] = f2bf(acc[mi][ni][j] * scale);
          }
        }
    } else {  // V: transpose via LDS (As region, stride 72), store vt[n][m]
      __syncthreads();
#pragma unroll
      for (int mi = 0; mi < 2; ++mi)
#pragma unroll
        for (int ni = 0; ni < 2; ++ni) {
          int nl = wn * 32 + ni * 16 + l15;
          int ml0 = wm * 32 + mi * 16 + l4 * 4;
          for (int j = 0; j < 4; ++j) As[nl * 72 + ml0 + j] = f2bf(acc[mi][ni][j]);
        }
      __syncthreads();
      for (int h = 0; h < 2; ++h) {
        int idx = t + h * 256;
        int nl = idx >> 3, c8 = idx & 7;
        int mg0 = m0 + c8 * 8;
        short* dstp = vt + (ncol0 + nl) * 256 + mg0;
        if (mg0 + 8 <= 210) {
          *(uint4*)dstp = *(const uint4*)&As[nl * 72 + c8 * 8];
        } else {
          for (int e = 0; e < 8; ++e)
            if (mg0 + e < 210) dstp[e] = As[nl * 72 + c8 * 8 + e];
        }
      }
    }
  }
  gg.sync();

  // ========== phase 2: S' = Qs@[K;wk]^T + table gather + softmax (blocks 0..7) ==========
#define SST 292
  if (b < 7) {
    short* As2 = (short*)smem;           // 32x128 = 8 KB
    short* Bs2 = (short*)(smem + 8192);  // 320x128 = 80 KB
    float* Ssh = (float*)(smem + 8192);  // 32 x SST fp32 = 37376 B, aliases Bs2
    int m0 = b * 32;
    f32x4 acc[2][5] = {};

    for (int k0 = 0; k0 < 1024; k0 += 128) {
      __syncthreads();
#pragma unroll
      for (int j = 0; j < 2; ++j) {
        int sj = t + j * 256;
        int r = sj >> 4, cg2 = (sj & 15) ^ (r & 7);
        async_cp16(qs + (size_t)(m0 + r) * 1024 + k0 + cg2 * 8, &As2[(w * 64 + j * 256) * 8]);
      }
#pragma unroll
      for (int j = 0; j < 20; ++j) {
        int sj = t + j * 256;
        int r = sj >> 4, cg2 = (sj & 15) ^ (r & 7);
        async_cp16(kwb + (size_t)r * 1024 + k0 + cg2 * 8, &Bs2[(w * 64 + j * 256) * 8]);
      }
      __syncthreads();
#pragma unroll
      for (int kk = 0; kk < 4; ++kk) {
        int c = kk * 4 + l4;
        bf16x8 a0 = *(const bf16x8*)&As2[SWZ(l15, c)];
        bf16x8 a1 = *(const bf16x8*)&As2[SWZ(16 + l15, c)];
#pragma unroll
        for (int ni = 0; ni < 5; ++ni) {
          bf16x8 bb = *(const bf16x8*)&Bs2[SWZ(w * 80 + ni * 16 + l15, c)];
          acc[0][ni] = MFMA16(a0, bb, acc[0][ni]);
          acc[1][ni] = MFMA16(a1, bb, acc[1][ni]);
        }
      }
    }
    __syncthreads();  // all Bs2 reads done before aliasing as Ssh
#pragma unroll
    for (int mi = 0; mi < 2; ++mi)
#pragma unroll
      for (int ni = 0; ni < 5; ++ni) {
        int col = w * 80 + ni * 16 + l15;
        if (col < 288) {
          int r0 = mi * 16 + l4 * 4;
          for (int jj = 0; jj < 4; ++jj) Ssh[(r0 + jj) * SST + col] = acc[mi][ni][jj];
        }
      }
    __syncthreads();

    int r = t >> 3, c = t & 7;  // 8 threads per row (within one wave)
    int row = m0 + r;
    float* Sr = Ssh + r * SST;
    if (row < 210) {
      const int* tr = table + row * 210;
      float mx = -1e30f;
      for (int j = c; j < 210; j += 8) {
        float lg = Sr[j] + Sr[210 + tr[j]];
        Sr[j] = lg;
        mx = fmaxf(mx, lg);
      }
      for (int o = 4; o; o >>= 1) mx = fmaxf(mx, __shfl_xor(mx, o, 8));
      float sum = 0.0f;
      for (int j = c; j < 210; j += 8) {
        float e = __expf(Sr[j] - mx);
        Sr[j] = e;
        sum += e;
      }
      for (int o = 4; o; o >>= 1) sum += __shfl_xor(sum, o, 8);
      float inv = 1.0f / sum;
      for (int j = c; j < 210; j += 8) {
        float a = Sr[j] * inv;
        outA[row * 210 + j] = a;
        Abf[row * 256 + j] = f2bf(a);
      }
      for (int j = 210 + c; j < 256; j += 8) Abf[row * 256 + j] = 0;
    } else {
      for (int j = c; j < 256; j += 8) Abf[row * 256 + j] = 0;
    }
  } else if (b == 7) {  // zero Abf rows 210..255 (46*256 shorts = 1472 uint4)
    for (int i = t; i < 1472; i += 256) ((uint4*)(Abf + 210 * 256))[i] = make_uint4(0, 0, 0, 0);
  }
  gg.sync();

  // ========== phase 3: AV = A @ V via vt[n][k] (blocks 0..63) ==========
  if (b < 64) {
    short* As = (short*)smem;
    short* Bs = (short*)(smem + 16384);
    int n0 = (b & 15) * 64, m0 = (b >> 4) * 64;
    int wm = w >> 1, wn = w & 1;
    f32x4 acc[2][2] = {};
    for (int k0 = 0; k0 < 256; k0 += 128) {
      __syncthreads();
#pragma unroll
      for (int j = 0; j < 4; ++j) {
        int sj = t + j * 256;
        int r = sj >> 4, cg2 = (sj & 15) ^ (r & 7);
        async_cp16(Abf + (size_t)(m0 + r) * 256 + k0 + cg2 * 8, &As[(w * 64 + j * 256) * 8]);
        async_cp16(vt + (size_t)(n0 + r) * 256 + k0 + cg2 * 8, &Bs[(w * 64 + j * 256) * 8]);
      }
      __syncthreads();
#pragma unroll
      for (int kk = 0; kk < 4; ++kk) {
        int c = kk * 4 + l4;
        int ra0 = wm * 32 + l15, ra1 = ra0 + 16;
        int rb0 = wn * 32 + l15, rb1 = rb0 + 16;
        bf16x8 a0 = *(const bf16x8*)&As[SWZ(ra0, c)];
        bf16x8 a1 = *(const bf16x8*)&As[SWZ(ra1, c)];
        bf16x8 b0 = *(const bf16x8*)&Bs[SWZ(rb0, c)];
        bf16x8 b1 = *(const bf16x8*)&Bs[SWZ(rb1, c)];
        acc[0][0] = MFMA16(a0, b0, acc[0][0]);
        acc[0][1] = MFMA16(a0, b1, acc[0][1]);
        acc[1][0] = MFMA16(a1, b0, acc[1][0]);
        acc[1][1] = MFMA16(a1, b1, acc[1][1]);
      }
    }
#pragma unroll
    for (int mi = 0; mi < 2; ++mi)
#pragma unroll
      for (int ni = 0; ni < 2; ++ni) {
        int r0 = m0 + wm * 32 + mi * 16 + l4 * 4;
        int c = n0 + wn * 32 + ni * 16 + l15;
        for (int j = 0; j < 4; ++j) {
          int r = r0 + j;
          if (r < 210) av[r * 1024 + c] = f2bf(acc[mi][ni][j]);
        }
      }
  }
  gg.sync();

  // ========== phase 4: Y = AV @ Wo via wot[n][k] (blocks 0..63), fp32 out ==========
  if (b < 64) {
    short* As = (short*)smem;
    short* Bs = (short*)(smem + 16384);
    int n0 = (b & 15) * 64, m0 = (b >> 4) * 64;
    int wm = w >> 1, wn = w & 1;
    f32x4 acc[2][2] = {};
    for (int k0 = 0; k0 < 1024; k0 += 128) {
      __syncthreads();
#pragma unroll
      for (int j = 0; j < 4; ++j) {
        int sj = t + j * 256;
        int r = sj >> 4, cg2 = (sj & 15) ^ (r & 7);
        async_cp16(av + (size_t)(m0 + r) * 1024 + k0 + cg2 * 8, &As[(w * 64 + j * 256) * 8]);
        async_cp16(wot + (size_t)(n0 + r) * 1024 + k0 + cg2 * 8, &Bs[(w * 64 + j * 256) * 8]);
      }
      __syncthreads();
#pragma unroll
      for (int kk = 0; kk < 4; ++kk) {
        int c = kk * 4 + l4;
        int ra0 = wm * 32 + l15, ra1 = ra0 + 16;
        int rb0 = wn * 32 + l15, rb1 = rb0 + 16;
        bf16x8 a0 = *(const bf16x8*)&As[SWZ(ra0, c)];
        bf16x8 a1 = *(const bf16x8*)&As[SWZ(ra1, c)];
        bf16x8 b0 = *(const bf16x8*)&Bs[SWZ(rb0, c)];
        bf16x8 b1 = *(const bf16x8*)&Bs[SWZ(rb1, c)];
        acc[0][0] = MFMA16(a0, b0, acc[0][0]);
        acc[0][1] = MFMA16(a0, b1, acc[0][1]);
        acc[1][0] = MFMA16(a1, b0, acc[1][0]);
        acc[1][1] = MFMA16(a1, b1, acc[1][1]);
      }
    }
#pragma unroll
    for (int mi = 0; mi < 2; ++mi)
#pragma unroll
      for (int ni = 0; ni < 2; ++ni) {
        int r0 = m0 + wm * 32 + mi * 16 + l4 * 4;
        int c = n0 + wn * 32 + ni * 16 + l15;
        for (int j = 0; j < 4; ++j) {
          int r = r0 + j;
          if (r < 210) outY[r * 1024 + c] = acc[mi][ni][j];
        }
      }
  }
}

extern "C" void kernel_launch(void* const* d_in, const int* in_sizes, int n_in,
                              void* d_out, int out_size, void* d_ws, size_t ws_size,
                              hipStream_t stream) {
  const float* Xmaj = (const float*)d_in[0];
  const float* Xmin = (const float*)d_in[1];
  const float* Wq = (const float*)d_in[2];
  const float* Wk = (const float*)d_in[3];
  const float* Wv = (const float*)d_in[4];
  const float* Wo = (const float*)d_in[5];
  const float* wk = (const float*)d_in[6];
  const int* table = (const int*)d_in[7];
  char* wsp = (char*)d_ws;
  float* outp = (float*)d_out;

  void* args[] = {(void*)&Xmaj, (void*)&Xmin, (void*)&Wq, (void*)&Wk, (void*)&Wv,
                  (void*)&Wo,   (void*)&wk,   (void*)&table, (void*)&wsp, (void*)&outp};
  hipLaunchCooperativeKernel((void*)k_fused, dim3(192), dim3(256), args, 0, stream);
}

// Round 7
// 146.098 us; speedup vs baseline: 1.7595x; 1.7595x over previous
//
#include <hip/hip_runtime.h>

typedef short bf16x8 __attribute__((ext_vector_type(8)));
typedef float f32x4 __attribute__((ext_vector_type(4)));

#define MFMA16(a, b, c) __builtin_amdgcn_mfma_f32_16x16x32_bf16(a, b, c, 0, 0, 0)

__device__ inline short f2bf(float f) {  // RNE, epilogue use
  unsigned u = __builtin_bit_cast(unsigned, f);
  u += 0x7FFFu + ((u >> 16) & 1u);
  return (short)(u >> 16);
}
// pack two fp32 -> 2 bf16 in one dword; round-half-up then v_perm byte-pack.
__device__ inline unsigned pack2(float lo, float hi) {
  unsigned a = __builtin_bit_cast(unsigned, lo) + 0x8000u;
  unsigned b = __builtin_bit_cast(unsigned, hi) + 0x8000u;
  return __builtin_amdgcn_perm(b, a, 0x07060302u);
}

// Async 16B global->LDS (zero VGPR round-trip). lds ptr must be the wave-uniform
// lane-0 base; HW writes lane i at base + 16*i (m104/m108).
__device__ inline void async_cp16(const void* g, void* l) {
  __builtin_amdgcn_global_load_lds(
      (const __attribute__((address_space(1))) unsigned int*)g,
      (__attribute__((address_space(3))) unsigned int*)l, 16, 0, 0);
}

// XOR-swizzled LDS tile: slot (r,c) holds global chunk c^(r&7). Staging lane-linear
// (conflict-free); frag ds_read_b128 spreads 8 lanes per 4-bank group (minimum).
#define SWZ(r, c) ((((r) << 4) + ((c) ^ ((r) & 7))) << 3)

// ---------------------------------------------------------------------------
// ws layout (bytes) — poison outside written regions is finite bf16, audited safe:
//   xmaj_bf  0        : 256x2048 bf16   rows>=210 poison (feeds discarded acc rows)
//   xmin_bf  1048576  : 256x2048 bf16
//   qs       2097152  : 256x1024 bf16   Qs (pre-scaled 1/32); rows>=210 poison
//   kwb      2621440  : 320x1024 bf16   0..209=K, 210..274=wk, 275..287=0, 288+ poison
//   vt       3276800  : 1024x256 bf16   V^T [n][m], cols>=210 poison (never read)
//   Abf      3801088  : 256x256  bf16   A padded, zeros outside 210x210
//   av       3932160  : 256x1024 bf16   A@V, rows>=210 poison (feeds discarded rows)
//   wqt      4743168  : 1024x2048 bf16  Wq^T
//   wkt      8937472  : 1024x2048 bf16  Wk^T
//   wvt      13131776 : 1024x2048 bf16  Wv^T
//   wot      17326080 : 1024x1024 bf16  Wo^T
// ---------------------------------------------------------------------------

// Prep: blocks [0,512) convert X_major/X_minor/wk to bf16, zero kwb pad rows and
// Abf tail rows; blocks [512,2048) transpose+convert Wq/Wk/Wv; [2048,2304) Wo.
__global__ __launch_bounds__(256) void k_prep(const float* __restrict__ xmaj,
                                              const float* __restrict__ xmin,
                                              const float* __restrict__ wkin,
                                              const float* __restrict__ Wq,
                                              const float* __restrict__ Wk,
                                              const float* __restrict__ Wv,
                                              const float* __restrict__ Wo,
                                              short* __restrict__ xmaj_bf,
                                              short* __restrict__ xmin_bf,
                                              short* __restrict__ kwb,
                                              short* __restrict__ Abf,
                                              short* __restrict__ wqt,
                                              short* __restrict__ wkt,
                                              short* __restrict__ wvt,
                                              short* __restrict__ wot) {
  __shared__ short tile[64][72];  // stride 72 shorts = 144 B: 16B-aligned rows
  int b = blockIdx.x, t = threadIdx.x;
  if (b < 512) {
    int idx = b * 256 + t;
    if (idx < 107520) {  // 210*2048/4
      float4 v = ((const float4*)xmaj)[idx];
      ((uint2*)xmaj_bf)[idx] = make_uint2(pack2(v.x, v.y), pack2(v.z, v.w));
      float4 u = ((const float4*)xmin)[idx];
      ((uint2*)xmin_bf)[idx] = make_uint2(pack2(u.x, u.y), pack2(u.z, u.w));
    }
    if (idx < 16640) {  // 65*1024/4
      float4 v = ((const float4*)wkin)[idx];
      ((uint2*)(kwb + 210 * 1024))[idx] = make_uint2(pack2(v.x, v.y), pack2(v.z, v.w));
    }
    if (idx < 1664) ((uint4*)(kwb + 275 * 1024))[idx] = make_uint4(0, 0, 0, 0);
    if (idx < 1472)  // zero Abf rows 210..255 (46*256 shorts)
      ((uint4*)(Abf + 210 * 256))[idx] = make_uint4(0, 0, 0, 0);
    return;
  }
  const float* W;
  short* Wt;
  int kt, nt, dstK;
  if (b < 2048) {
    int wi = (b - 512) >> 9, tl = (b - 512) & 511;
    W = wi == 0 ? Wq : (wi == 1 ? Wk : Wv);
    Wt = wi == 0 ? wqt : (wi == 1 ? wkt : wvt);
    kt = tl >> 4; nt = tl & 15; dstK = 2048;
  } else {
    int tl = b - 2048;
    W = Wo; Wt = wot; kt = tl >> 4; nt = tl & 15; dstK = 1024;
  }
  int k0 = kt * 64, n0 = nt * 64;
  int kp = t >> 4, nl4 = (t & 15) * 4;
  for (int h = 0; h < 2; ++h) {
    int kpp = kp + h * 16;
    const float* g = W + (size_t)(k0 + 2 * kpp) * 1024 + n0 + nl4;
    float4 u = *(const float4*)g;
    float4 v = *(const float4*)(g + 1024);
    *(unsigned*)&tile[nl4 + 0][2 * kpp] = pack2(u.x, v.x);
    *(unsigned*)&tile[nl4 + 1][2 * kpp] = pack2(u.y, v.y);
    *(unsigned*)&tile[nl4 + 2][2 * kpp] = pack2(u.z, v.z);
    *(unsigned*)&tile[nl4 + 3][2 * kpp] = pack2(u.w, v.w);
  }
  __syncthreads();
  int nl = t >> 2, cq = t & 3;
  for (int h = 0; h < 2; ++h) {
    int c = cq + h * 4;
    *(uint4*)(Wt + (size_t)(n0 + nl) * dstK + k0 + c * 8) = *(const uint4*)&tile[nl][c * 8];
  }
}

// QKV: [Xmaj@Wq*scale | Xmin@Wk | Xmin@Wv], all-bf16 async staging, BK=128, 16 phases.
// 192 blocks, XCD swizzle: 4 m-tiles sharing a weight tile land on one XCD.
__global__ __launch_bounds__(256, 1) void k_qkv(const short* __restrict__ xmaj,
                                                const short* __restrict__ xmin,
                                                const short* __restrict__ wqt,
                                                const short* __restrict__ wkt,
                                                const short* __restrict__ wvt,
                                                short* __restrict__ qs,
                                                short* __restrict__ kwb,
                                                short* __restrict__ vt) {
  __shared__ short As[64 * 128];
  __shared__ short Bs[64 * 128];
  int b = blockIdx.x, t = threadIdx.x;
  int x = b & 7, s = b >> 3;
  int ntile = x * 6 + (s >> 2), mtile = s & 3;
  int nn0 = ntile * 64;
  int mat = nn0 >> 10, ncol0 = nn0 & 1023, m0 = mtile * 64;
  const short* A = (mat == 0) ? xmaj : xmin;
  const short* Bt = (mat == 0) ? wqt : (mat == 1 ? wkt : wvt);
  int lane = t & 63, w = t >> 6;
  int wm = w >> 1, wn = w & 1;
  int l15 = lane & 15, l4 = lane >> 4;
  f32x4 acc[2][2] = {};

  for (int k0 = 0; k0 < 2048; k0 += 128) {
    __syncthreads();
#pragma unroll
    for (int j = 0; j < 4; ++j) {
      int sj = t + j * 256;
      int r = sj >> 4, cg = (sj & 15) ^ (r & 7);
      async_cp16(A + (size_t)(m0 + r) * 2048 + k0 + cg * 8, &As[(w * 64 + j * 256) * 8]);
    }
#pragma unroll
    for (int j = 0; j < 4; ++j) {
      int sj = t + j * 256;
      int r = sj >> 4, cg = (sj & 15) ^ (r & 7);
      async_cp16(Bt + (size_t)(ncol0 + r) * 2048 + k0 + cg * 8, &Bs[(w * 64 + j * 256) * 8]);
    }
    __syncthreads();
#pragma unroll
    for (int kk = 0; kk < 4; ++kk) {
      int c = kk * 4 + l4;
      int ra0 = wm * 32 + l15, ra1 = ra0 + 16;
      int rb0 = wn * 32 + l15, rb1 = rb0 + 16;
      bf16x8 a0 = *(const bf16x8*)&As[SWZ(ra0, c)];
      bf16x8 a1 = *(const bf16x8*)&As[SWZ(ra1, c)];
      bf16x8 b0 = *(const bf16x8*)&Bs[SWZ(rb0, c)];
      bf16x8 b1 = *(const bf16x8*)&Bs[SWZ(rb1, c)];
      acc[0][0] = MFMA16(a0, b0, acc[0][0]);
      acc[0][1] = MFMA16(a0, b1, acc[0][1]);
      acc[1][0] = MFMA16(a1, b0, acc[1][0]);
      acc[1][1] = MFMA16(a1, b1, acc[1][1]);
    }
  }

  if (mat < 2) {
    float scale = (mat == 0) ? 0.03125f : 1.0f;
    short* dst = (mat == 0) ? qs : kwb;
#pragma unroll
    for (int mi = 0; mi < 2; ++mi)
#pragma unroll
      for (int ni = 0; ni < 2; ++ni) {
        int r0 = m0 + wm * 32 + mi * 16 + l4 * 4;
        int c = ncol0 + wn * 32 + ni * 16 + l15;
        for (int j = 0; j < 4; ++j) {
          int r = r0 + j;
          if (r < 210) dst[r * 1024 + c] = f2bf(acc[mi][ni][j] * scale);
        }
      }
  } else {
    // V: transpose via LDS (reuse As, stride 72 for aligned uint4 reads), store Vt[n][m]
    __syncthreads();
#pragma unroll
    for (int mi = 0; mi < 2; ++mi)
#pragma unroll
      for (int ni = 0; ni < 2; ++ni) {
        int nl = wn * 32 + ni * 16 + l15;
        int ml0 = wm * 32 + mi * 16 + l4 * 4;
        for (int j = 0; j < 4; ++j) As[nl * 72 + ml0 + j] = f2bf(acc[mi][ni][j]);
      }
    __syncthreads();
    for (int h = 0; h < 2; ++h) {
      int idx = t + h * 256;
      int nl = idx >> 3, c8 = idx & 7;
      int mg0 = m0 + c8 * 8;
      short* dstp = vt + (ncol0 + nl) * 256 + mg0;
      if (mg0 + 8 <= 210) {
        *(uint4*)dstp = *(const uint4*)&As[nl * 72 + c8 * 8];
      } else {
        for (int e = 0; e < 8; ++e)
          if (mg0 + e < 210) dstp[e] = As[nl * 72 + c8 * 8 + e];
      }
    }
  }
}

// Fused S' + table-gather + softmax. 7 blocks x 32 rows. S'[32][288] computed into
// LDS (waves own 80-col strips; cols>=288 hit kwb poison -> finite, discarded),
// then gather+softmax in-block. No Sp global round-trip.
#define SST 292
__global__ __launch_bounds__(256, 1) void k_attn(const short* __restrict__ qs,
                                                 const short* __restrict__ kwb,
                                                 const int* __restrict__ table,
                                                 short* __restrict__ Abf,
                                                 float* __restrict__ outA) {
  __shared__ short As2[32 * 128];   // 8 KB
  __shared__ short Bs2[320 * 128];  // 80 KB; aliased by Ssh after K-loop
  float* Ssh = (float*)Bs2;         // 32 x SST fp32 = 37376 B
  int b = blockIdx.x, t = threadIdx.x;
  int lane = t & 63, w = t >> 6;
  int l15 = lane & 15, l4 = lane >> 4;
  int m0 = b * 32;
  f32x4 acc[2][5] = {};

  for (int k0 = 0; k0 < 1024; k0 += 128) {
    __syncthreads();
#pragma unroll
    for (int j = 0; j < 2; ++j) {
      int sj = t + j * 256;
      int r = sj >> 4, cg = (sj & 15) ^ (r & 7);
      async_cp16(qs + (size_t)(m0 + r) * 1024 + k0 + cg * 8, &As2[(w * 64 + j * 256) * 8]);
    }
#pragma unroll
    for (int j = 0; j < 20; ++j) {
      int sj = t + j * 256;
      int r = sj >> 4, cg = (sj & 15) ^ (r & 7);
      async_cp16(kwb + (size_t)r * 1024 + k0 + cg * 8, &Bs2[(w * 64 + j * 256) * 8]);
    }
    __syncthreads();
#pragma unroll
    for (int kk = 0; kk < 4; ++kk) {
      int c = kk * 4 + l4;
      bf16x8 a0 = *(const bf16x8*)&As2[SWZ(l15, c)];
      bf16x8 a1 = *(const bf16x8*)&As2[SWZ(16 + l15, c)];
#pragma unroll
      for (int ni = 0; ni < 5; ++ni) {
        bf16x8 bb = *(const bf16x8*)&Bs2[SWZ(w * 80 + ni * 16 + l15, c)];
        acc[0][ni] = MFMA16(a0, bb, acc[0][ni]);
        acc[1][ni] = MFMA16(a1, bb, acc[1][ni]);
      }
    }
  }
  __syncthreads();  // all Bs2 reads done before aliasing as Ssh
#pragma unroll
  for (int mi = 0; mi < 2; ++mi)
#pragma unroll
    for (int ni = 0; ni < 5; ++ni) {
      int col = w * 80 + ni * 16 + l15;
      if (col < 288) {
        int r0 = mi * 16 + l4 * 4;
        for (int jj = 0; jj < 4; ++jj) Ssh[(r0 + jj) * SST + col] = acc[mi][ni][jj];
      }
    }
  __syncthreads();

  int r = t >> 3, c = t & 7;  // 8 threads per row (same wave)
  int row = m0 + r;
  float* Sr = Ssh + r * SST;
  if (row < 210) {
    const int* tr = table + row * 210;
    float mx = -1e30f;
    for (int j = c; j < 210; j += 8) {
      float lg = Sr[j] + Sr[210 + tr[j]];  // gather targets 210..274 never overwritten
      Sr[j] = lg;
      mx = fmaxf(mx, lg);
    }
    for (int o = 4; o; o >>= 1) mx = fmaxf(mx, __shfl_xor(mx, o, 8));
    float sum = 0.0f;
    for (int j = c; j < 210; j += 8) {
      float e = __expf(Sr[j] - mx);
      Sr[j] = e;
      sum += e;
    }
    for (int o = 4; o; o >>= 1) sum += __shfl_xor(sum, o, 8);
    float inv = 1.0f / sum;
    for (int j = c; j < 210; j += 8) {
      float a = Sr[j] * inv;
      outA[row * 210 + j] = a;
      Abf[row * 256 + j] = f2bf(a);
    }
    for (int j = 210 + c; j < 256; j += 8) Abf[row * 256 + j] = 0;
  } else {
    for (int j = c; j < 256; j += 8) Abf[row * 256 + j] = 0;
  }
}

// AV = A(pad bf16) @ V via vt[n][k]. 64x64 tiles, grid(16,4), K=256, 2 phases.
__global__ __launch_bounds__(256, 1) void k_av(const short* __restrict__ Abf,
                                               const short* __restrict__ vt,
                                               short* __restrict__ av) {
  __shared__ short As[64 * 128];
  __shared__ short Bs[64 * 128];
  int n0 = blockIdx.x * 64, m0 = blockIdx.y * 64;
  int t = threadIdx.x, lane = t & 63, w = t >> 6;
  int wm = w >> 1, wn = w & 1;
  int l15 = lane & 15, l4 = lane >> 4;
  f32x4 acc[2][2] = {};

  for (int k0 = 0; k0 < 256; k0 += 128) {
    __syncthreads();
#pragma unroll
    for (int j = 0; j < 4; ++j) {
      int sj = t + j * 256;
      int r = sj >> 4, cg = (sj & 15) ^ (r & 7);
      async_cp16(Abf + (size_t)(m0 + r) * 256 + k0 + cg * 8, &As[(w * 64 + j * 256) * 8]);
      async_cp16(vt + (size_t)(n0 + r) * 256 + k0 + cg * 8, &Bs[(w * 64 + j * 256) * 8]);
    }
    __syncthreads();
#pragma unroll
    for (int kk = 0; kk < 4; ++kk) {
      int c = kk * 4 + l4;
      int ra0 = wm * 32 + l15, ra1 = ra0 + 16;
      int rb0 = wn * 32 + l15, rb1 = rb0 + 16;
      bf16x8 a0 = *(const bf16x8*)&As[SWZ(ra0, c)];
      bf16x8 a1 = *(const bf16x8*)&As[SWZ(ra1, c)];
      bf16x8 b0 = *(const bf16x8*)&Bs[SWZ(rb0, c)];
      bf16x8 b1 = *(const bf16x8*)&Bs[SWZ(rb1, c)];
      acc[0][0] = MFMA16(a0, b0, acc[0][0]);
      acc[0][1] = MFMA16(a0, b1, acc[0][1]);
      acc[1][0] = MFMA16(a1, b0, acc[1][0]);
      acc[1][1] = MFMA16(a1, b1, acc[1][1]);
    }
  }
#pragma unroll
  for (int mi = 0; mi < 2; ++mi)
#pragma unroll
    for (int ni = 0; ni < 2; ++ni) {
      int r0 = m0 + wm * 32 + mi * 16 + l4 * 4;
      int c = n0 + wn * 32 + ni * 16 + l15;
      for (int j = 0; j < 4; ++j) {
        int r = r0 + j;
        if (r < 210) av[r * 1024 + c] = f2bf(acc[mi][ni][j]);
      }
    }
}

// Y = AV @ Wo via wot[n][k]. 64x64 tiles, grid(16,4), K=1024, 8 phases. fp32 out.
__global__ __launch_bounds__(256, 1) void k_y(const short* __restrict__ av,
                                              const short* __restrict__ wot,
                                              float* __restrict__ outY) {
  __shared__ short As[64 * 128];
  __shared__ short Bs[64 * 128];
  int n0 = blockIdx.x * 64, m0 = blockIdx.y * 64;
  int t = threadIdx.x, lane = t & 63, w = t >> 6;
  int wm = w >> 1, wn = w & 1;
  int l15 = lane & 15, l4 = lane >> 4;
  f32x4 acc[2][2] = {};

  for (int k0 = 0; k0 < 1024; k0 += 128) {
    __syncthreads();
#pragma unroll
    for (int j = 0; j < 4; ++j) {
      int sj = t + j * 256;
      int r = sj >> 4, cg = (sj & 15) ^ (r & 7);
      async_cp16(av + (size_t)(m0 + r) * 1024 + k0 + cg * 8, &As[(w * 64 + j * 256) * 8]);
      async_cp16(wot + (size_t)(n0 + r) * 1024 + k0 + cg * 8, &Bs[(w * 64 + j * 256) * 8]);
    }
    __syncthreads();
#pragma unroll
    for (int kk = 0; kk < 4; ++kk) {
      int c = kk * 4 + l4;
      int ra0 = wm * 32 + l15, ra1 = ra0 + 16;
      int rb0 = wn * 32 + l15, rb1 = rb0 + 16;
      bf16x8 a0 = *(const bf16x8*)&As[SWZ(ra0, c)];
      bf16x8 a1 = *(const bf16x8*)&As[SWZ(ra1, c)];
      bf16x8 b0 = *(const bf16x8*)&Bs[SWZ(rb0, c)];
      bf16x8 b1 = *(const bf16x8*)&Bs[SWZ(rb1, c)];
      acc[0][0] = MFMA16(a0, b0, acc[0][0]);
      acc[0][1] = MFMA16(a0, b1, acc[0][1]);
      acc[1][0] = MFMA16(a1, b0, acc[1][0]);
      acc[1][1] = MFMA16(a1, b1, acc[1][1]);
    }
  }
#pragma unroll
  for (int mi = 0; mi < 2; ++mi)
#pragma unroll
    for (int ni = 0; ni < 2; ++ni) {
      int r0 = m0 + wm * 32 + mi * 16 + l4 * 4;
      int c = n0 + wn * 32 + ni * 16 + l15;
      for (int j = 0; j < 4; ++j) {
        int r = r0 + j;
        if (r < 210) outY[r * 1024 + c] = acc[mi][ni][j];
      }
    }
}

extern "C" void kernel_launch(void* const* d_in, const int* in_sizes, int n_in,
                              void* d_out, int out_size, void* d_ws, size_t ws_size,
                              hipStream_t stream) {
  const float* Xmaj = (const float*)d_in[0];
  const float* Xmin = (const float*)d_in[1];
  const float* Wq = (const float*)d_in[2];
  const float* Wk = (const float*)d_in[3];
  const float* Wv = (const float*)d_in[4];
  const float* Wo = (const float*)d_in[5];
  const float* wk = (const float*)d_in[6];
  const int* table = (const int*)d_in[7];

  char* ws = (char*)d_ws;
  short* xmaj_bf = (short*)(ws + 0);
  short* xmin_bf = (short*)(ws + 1048576);
  short* qs = (short*)(ws + 2097152);
  short* kwb = (short*)(ws + 2621440);
  short* vt = (short*)(ws + 3276800);
  short* Abf = (short*)(ws + 3801088);
  short* av = (short*)(ws + 3932160);
  short* wqt = (short*)(ws + 4743168);
  short* wkt = (short*)(ws + 8937472);
  short* wvt = (short*)(ws + 13131776);
  short* wot = (short*)(ws + 17326080);

  float* outY = (float*)d_out;           // 210*1024 fp32
  float* outA = (float*)d_out + 215040;  // 210*210 fp32

  k_prep<<<2304, 256, 0, stream>>>(Xmaj, Xmin, wk, Wq, Wk, Wv, Wo,
                                   xmaj_bf, xmin_bf, kwb, Abf, wqt, wkt, wvt, wot);
  k_qkv<<<192, 256, 0, stream>>>(xmaj_bf, xmin_bf, wqt, wkt, wvt, qs, kwb, vt);
  k_attn<<<7, 256, 0, stream>>>(qs, kwb, table, Abf, outA);
  k_av<<<dim3(16, 4), 256, 0, stream>>>(Abf, vt, av);
  k_y<<<dim3(16, 4), 256, 0, stream>>>(av, wot, outY);
}